// Round 1
// baseline (323.756 us; speedup 1.0000x reference)
//
#include <hip/hip_runtime.h>

#define MAXG 4
#define CPB 8                        // channels per block = 4 pairs
#define UCOLS 33                     // region cols 0..32 per row
#define PLANE 991                    // float2 per pair-plane: 30*33=990 used +1 pad (odd)
                                     // 2*991 mod 32 = 30 -> planes p=0..3 start on banks {0,30,28,26}: disjoint from 8q lattice
#define S2LEN (4 * PLANE)            // 3964 float2 = 31712 B (+tables = 32608 B total -> 5 blocks/CU)

// Block = (roi, 8-channel group), 256 threads.
// LDS holds the ROI region as FOUR channel-pair planes: float2{ch2p, ch2p+1} at
// index p*PLANE + row*33 + col. One phase-2 thread = 1 pixel x 2 channels: each
// bilinear corner is a single ds_read_b64 and weights/addresses amortize 2x.
// vs previous version: pair-interleaved stride-5 layout (39.7 KB, 4 blocks/CU)
// replaced by plane-separated layout (31.8 KB, 5 blocks/CU) for +25% occupancy.
__global__ __launch_bounds__(256, 5) void roi_align_kernel(
    const float* __restrict__ feat,
    const float* __restrict__ rois,
    float* __restrict__ out,
    int C, int H, int W)
{
    const int n    = blockIdx.x;
    const int cblk = blockIdx.y;
    const int t    = threadIdx.x;

    __shared__ float2 s_feat2[S2LEN];
    __shared__ int4   s_ypack[28];   // {(lo-y0)*33, (hi-y0)*33, bits(wy0), bits(wy1)}
    __shared__ int4   s_xpack[28];   // {(xlo-x0a), (xhi-x0a), bits(wx0), bits(wx1)}

    const float* roi = rois + (size_t)n * 5;
    const int   b  = (int)roi[0];
    const float x1 = roi[1], y1 = roi[2], x2 = roi[3], y2 = roi[4];
    const float roi_w = fmaxf(x2 - x1, 1.0f);
    const float roi_h = fmaxf(y2 - y1, 1.0f);
    const float bin_h = roi_h / 7.0f;
    const float bin_w = roi_w / 7.0f;
    int gh = (int)ceilf(roi_h / 7.0f); gh = min(max(gh, 1), MAXG);
    int gw = (int)ceilf(roi_w / 7.0f); gw = min(max(gw, 1), MAXG);
    const float inv_count = 1.0f / (float)(gh * gw);

    auto lo_of = [](float pos, int size) {
        float p = fmaxf(pos, 0.0f);
        return min((int)floorf(p), size - 1);
    };
    const int y0 = lo_of(y1 + 0.5f * bin_h / (float)gh, H);
    const int yE = min(lo_of(y1 + 6.0f * bin_h + ((float)(gh - 1) + 0.5f) * bin_h / (float)gh, H) + 1, H - 1);
    const int x0 = lo_of(x1 + 0.5f * bin_w / (float)gw, W);
    const int xE = min(lo_of(x1 + 6.0f * bin_w + ((float)(gw - 1) + 0.5f) * bin_w / (float)gw, W) + 1, W - 1);
    const int rh    = min(yE - y0 + 1, 30);
    const int x0a   = x0 & ~3;                   // 16B-align region start
    const int spanA = min(xE - x0a + 1, 33);     // cols needed from x0a (<=33)
    const int CM    = W - 4 - x0a;               // max in-row aligned quad start

    // --- geometry tables (y offsets premultiplied into float2-index units)
    if (t < 28) {
        const int py = t >> 2, g = t & 3;
        float pos  = y1 + (float)py * bin_h + ((float)g + 0.5f) * bin_h / (float)gh;
        bool valid = (pos >= -1.0f) && (pos <= (float)H);
        float p = fmaxf(pos, 0.0f);
        int lo  = min((int)floorf(p), H - 1);
        int hi  = min(lo + 1, H - 1);
        if (lo >= H - 1) p = (float)(H - 1);
        float frac = p - (float)lo;
        float m = valid ? 1.0f : 0.0f;
        s_ypack[t] = make_int4((lo - y0) * UCOLS, (hi - y0) * UCOLS,
                               __float_as_int((1.0f - frac) * m),
                               __float_as_int(frac * m));
    } else if (t < 56) {
        const int u = t - 28;
        const int px = u >> 2, g = u & 3;
        float pos  = x1 + (float)px * bin_w + ((float)g + 0.5f) * bin_w / (float)gw;
        bool valid = (pos >= -1.0f) && (pos <= (float)W);
        float p = fmaxf(pos, 0.0f);
        int lo  = min((int)floorf(p), W - 1);
        int hi  = min(lo + 1, W - 1);
        if (lo >= W - 1) p = (float)(W - 1);
        float frac = p - (float)lo;
        float m = valid ? 1.0f : 0.0f;
        s_xpack[u] = make_int4(lo - x0a, hi - x0a,
                               __float_as_int((1.0f - frac) * m),
                               __float_as_int(frac * m));
    }

    // --- staging: transpose [ch][row][col] -> per-pair planes in LDS
    // slot: pair p = t&3, quad q = (t>>2)&7, row base r0 = t>>5 (stride 8)
    {
        const int  p    = t & 3;
        const int  q    = (t >> 2) & 7;
        const int  r0   = t >> 5;
        const int  q4   = q << 2;
        const bool qon  = (q4 < spanA);
        const int  colA = min(q4, CM);           // in-row aligned; dup writes benign
        const bool tail = (q == 7) && (spanA == 33);

        const size_t HW = (size_t)H * W;
        const int c0 = cblk * CPB;
        const float* fbase = feat + ((size_t)b * C + c0) * HW + (size_t)y0 * W + x0a;
        const float* ga = fbase + (size_t)(2 * p) * HW;
        float2* sb = s_feat2 + p * PLANE;

        #pragma unroll
        for (int k = 0; k < 4; ++k) {
            const int r = r0 + (k << 3);
            if (r < rh) {
                const float* gp = ga + (size_t)r * W;
                if (qon) {
                    const float4 va = *(const float4*)(gp + colA);
                    const float4 vb = *(const float4*)(gp + HW + colA);
                    float2* sp = sb + r * UCOLS + colA;
                    sp[0] = make_float2(va.x, vb.x);
                    sp[1] = make_float2(va.y, vb.y);
                    sp[2] = make_float2(va.z, vb.z);
                    sp[3] = make_float2(va.w, vb.w);
                }
                if (tail) {                      // col 32 (x0a+32 <= W-1 here)
                    sb[r * UCOLS + 32] = make_float2(gp[32], gp[HW + 32]);
                }
            }
        }
    }
    __syncthreads();

    // --- compute: thread = (pixel t>>2, channel-pair t&3); taps are b64 reads
    if (t < 196) {
        const int p   = t & 3;
        const int pix = t >> 2;
        const int py  = pix / 7;
        const int px  = pix - py * 7;
        const float2* sp = s_feat2 + p * PLANE;

        int4 xp[4];
        #pragma unroll
        for (int g = 0; g < 4; ++g) xp[g] = s_xpack[(px << 2) + g];

        float ax = 0.0f, ay = 0.0f;
        #pragma unroll
        for (int gy = 0; gy < MAXG; ++gy) {
            if (gy < gh) {
                const int4 yp = s_ypack[(py << 2) + gy];
                const float wy0 = __int_as_float(yp.z);
                const float wy1 = __int_as_float(yp.w);
                #pragma unroll
                for (int gx = 0; gx < MAXG; ++gx) {
                    if (gx < gw) {
                        const float wx0 = __int_as_float(xp[gx].z);
                        const float wx1 = __int_as_float(xp[gx].w);
                        const float2 v00 = sp[yp.x + xp[gx].x];
                        const float2 v01 = sp[yp.x + xp[gx].y];
                        const float2 v10 = sp[yp.y + xp[gx].x];
                        const float2 v11 = sp[yp.y + xp[gx].y];
                        ax += wy0 * (wx0 * v00.x + wx1 * v01.x)
                            + wy1 * (wx0 * v10.x + wx1 * v11.x);
                        ay += wy0 * (wx0 * v00.y + wx1 * v01.y)
                            + wy1 * (wx0 * v10.y + wx1 * v11.y);
                    }
                }
            }
        }
        const size_t ob = ((size_t)n * C + cblk * CPB + 2 * p) * 49 + pix;
        out[ob]      = ax * inv_count;   // channel 2p
        out[ob + 49] = ay * inv_count;   // channel 2p+1
    }
}

extern "C" void kernel_launch(void* const* d_in, const int* in_sizes, int n_in,
                              void* d_out, int out_size, void* d_ws, size_t ws_size,
                              hipStream_t stream) {
    const float* feat = (const float*)d_in[0];
    const float* rois = (const float*)d_in[1];
    float* out = (float*)d_out;

    const int C = 256, H = 200, W = 272;
    const int N = in_sizes[1] / 5;   // 512

    dim3 grid(N, C / CPB);           // 512 x 32
    roi_align_kernel<<<grid, 256, 0, stream>>>(feat, rois, out, C, H, W);
}